// Round 4
// baseline (506.162 us; speedup 1.0000x reference)
//
#include <hip/hip_runtime.h>
#include <math.h>

// CLIP transformer layer: B=8 S=1024 D=1024 H=16 DH=64 FF=4096, fp32 I/O,
// bf16 MFMA internals. Round 4: 32x32x16 MFMA GEMM, sigmoid-GELU epilogue,
// V-transpose fused into QKV epilogue, merged weight converts.

typedef __bf16 bf16_t;
typedef __bf16 bf16x4 __attribute__((ext_vector_type(4)));
typedef __bf16 bf16x8 __attribute__((ext_vector_type(8)));
typedef float f32x4 __attribute__((ext_vector_type(4)));
typedef float f32x16 __attribute__((ext_vector_type(16)));

// ---------------------------------------------------------------- helpers
__device__ __forceinline__ void async16(const void* g, void* l) {
    // global -> LDS direct DMA, 16B/lane. LDS dest is wave-uniform base + lane*16.
    __builtin_amdgcn_global_load_lds(
        (const __attribute__((address_space(1))) void*)g,
        (__attribute__((address_space(3))) void*)l,
        16, 0, 0);
}

// ---------------------------------------------------------------- fp32 -> bf16 convert (all 4 weights, one dispatch)
__global__ __launch_bounds__(256) void f2b_all(
    const float* __restrict__ s0, const float* __restrict__ s1,
    const float* __restrict__ s2, const float* __restrict__ s3,
    bf16_t* __restrict__ d0, bf16_t* __restrict__ d1,
    bf16_t* __restrict__ d2, bf16_t* __restrict__ d3) {
    const int g = blockIdx.x * 256 + threadIdx.x;  // float4-group index
    const float* s;
    bf16_t* d;
    int off;
    if (g < 786432)       { s = s0; d = d0; off = g; }            // w_qkv 3M elem
    else if (g < 1048576) { s = s1; d = d1; off = g - 786432; }   // w_o 1M
    else if (g < 2097152) { s = s2; d = d2; off = g - 1048576; }  // w1 4M
    else                  { s = s3; d = d3; off = g - 2097152; }  // w2 4M
    const int i = off * 4;
    const float4 v = *(const float4*)(s + i);
    bf16x4 o;
    o[0] = (bf16_t)v.x; o[1] = (bf16_t)v.y; o[2] = (bf16_t)v.z; o[3] = (bf16_t)v.w;
    *(bf16x4*)(d + i) = o;
}

// ---------------------------------------------------------------- LayerNorm (row of 1024) -> bf16
__global__ __launch_bounds__(256) void ln_bf16(const float* __restrict__ x,
                                               const float* __restrict__ g,
                                               const float* __restrict__ bb,
                                               bf16_t* __restrict__ out) {
    const int tid = threadIdx.x;
    const int row = blockIdx.x;
    const float4 xv = *(const float4*)(x + row * 1024 + tid * 4);
    float s1 = xv.x + xv.y + xv.z + xv.w;
    float s2 = xv.x * xv.x + xv.y * xv.y + xv.z * xv.z + xv.w * xv.w;
#pragma unroll
    for (int m = 32; m >= 1; m >>= 1) {
        s1 += __shfl_xor(s1, m);
        s2 += __shfl_xor(s2, m);
    }
    __shared__ float r1[4], r2[4];
    const int wid = tid >> 6, lane = tid & 63;
    if (lane == 0) { r1[wid] = s1; r2[wid] = s2; }
    __syncthreads();
    s1 = r1[0] + r1[1] + r1[2] + r1[3];
    s2 = r2[0] + r2[1] + r2[2] + r2[3];
    const float mu = s1 * (1.0f / 1024.0f);
    const float var = s2 * (1.0f / 1024.0f) - mu * mu;
    const float rs = rsqrtf(var + 1e-5f);
    const float4 gv = *(const float4*)(g + tid * 4);
    const float4 bv = *(const float4*)(bb + tid * 4);
    bf16x4 o;
    o[0] = (bf16_t)((xv.x - mu) * rs * gv.x + bv.x);
    o[1] = (bf16_t)((xv.y - mu) * rs * gv.y + bv.y);
    o[2] = (bf16_t)((xv.z - mu) * rs * gv.z + bv.z);
    o[3] = (bf16_t)((xv.w - mu) * rs * gv.w + bv.w);
    *(bf16x4*)(out + row * 1024 + tid * 4) = o;
}

// ---------------------------------------------------------------- GEMM: C[M,N] = A[M,K] @ W[N,K]^T + bias
// 128x128 tile, BK=64, XOR-swizzled LDS, 2x2 of 32x32x16 MFMA per wave.
// MODE 0: bias -> bf16; MODE 1: bias+gelu(sigmoid form) -> bf16;
// MODE 2: bias+residual -> fp32; MODE 3: QKV (bias -> bf16 for Q/K cols,
//         V cols transposed straight into vt[bh][d][s]).
template <int MODE>
__global__ __launch_bounds__(256, 2) void gemm_bt(
    const bf16_t* __restrict__ A, const bf16_t* __restrict__ W,
    const float* __restrict__ bias, const float* __restrict__ resid,
    bf16_t* __restrict__ outb, float* __restrict__ outf,
    bf16_t* __restrict__ vt, int N, int K) {
    __shared__ bf16_t As[128 * 64];
    __shared__ bf16_t Bs[128 * 64];
    const int tid = threadIdx.x;
    const int w = tid >> 6;
    const int lane = tid & 63;
    const int l31 = lane & 31;
    const int kh = lane >> 5;  // k-half

    // block swizzle: groups of 8 m-blocks share the n-column (W-tile reuse)
    const int nbn = N >> 7;
    const int per = 8 * nbn;
    const int lid = blockIdx.x;
    const int bm = (lid / per) * 8 + (lid % per) % 8;
    const int bn = (lid % per) / 8;
    const int m0 = bm * 128;
    const int n0 = bn * 128;
    const int wm = (w & 1) * 64;
    const int wn = (w >> 1) * 64;

    // staging: 4 calls/wave per operand; chunk c = q*256 + w*64 + lane (16B each).
    // LDS slot (row r, seg s) holds global k-seg (s ^ (r&7)).
    int rr[4], so[4];
#pragma unroll
    for (int q = 0; q < 4; q++) {
        const int c = q * 256 + w * 64 + lane;
        rr[q] = c >> 3;
        so[q] = ((c & 7) ^ (rr[q] & 7)) * 8;
    }
    const bf16_t* pA[4];
    const bf16_t* pB[4];
#pragma unroll
    for (int q = 0; q < 4; q++) {
        pA[q] = A + (size_t)(m0 + rr[q]) * K + so[q];
        pB[q] = W + (size_t)(n0 + rr[q]) * K + so[q];
    }

    f32x16 acc[2][2] = {};

    for (int k0 = 0; k0 < K; k0 += 64) {
#pragma unroll
        for (int q = 0; q < 4; q++) {
            async16(pA[q], As + q * 2048 + w * 512);
            async16(pB[q], Bs + q * 2048 + w * 512);
            pA[q] += 64; pB[q] += 64;
        }
        __syncthreads();  // drains vmcnt -> LDS tiles visible

        // fragments: A[m=l31][k=kh*8+j] per 16-k-step; swizzled slot lookup
        bf16x8 af[2][4], bff[2][4];
#pragma unroll
        for (int mb = 0; mb < 2; mb++) {
            const int r = wm + mb * 32 + l31;
#pragma unroll
            for (int ks = 0; ks < 4; ks++) {
                const int slot = (ks * 2 + kh) ^ (r & 7);
                af[mb][ks] = *(const bf16x8*)(As + r * 64 + slot * 8);
            }
        }
#pragma unroll
        for (int nb = 0; nb < 2; nb++) {
            const int r = wn + nb * 32 + l31;
#pragma unroll
            for (int ks = 0; ks < 4; ks++) {
                const int slot = (ks * 2 + kh) ^ (r & 7);
                bff[nb][ks] = *(const bf16x8*)(Bs + r * 64 + slot * 8);
            }
        }
#pragma unroll
        for (int ks = 0; ks < 4; ks++)
#pragma unroll
            for (int mb = 0; mb < 2; mb++)
#pragma unroll
                for (int nb = 0; nb < 2; nb++)
                    acc[mb][nb] = __builtin_amdgcn_mfma_f32_32x32x16_bf16(
                        af[mb][ks], bff[nb][ks], acc[mb][nb], 0, 0, 0);
        __syncthreads();  // protect LDS from next iteration's staging
    }

    // epilogue: 32x32 C/D layout col=lane&31, row=(reg&3)+8*(reg>>2)+4*(lane>>5)
#pragma unroll
    for (int mb = 0; mb < 2; mb++) {
#pragma unroll
        for (int nb = 0; nb < 2; nb++) {
            const int col = n0 + wn + nb * 32 + l31;
            const float bcol = bias[col];
#pragma unroll
            for (int g = 0; g < 4; g++) {
                const int row0 = m0 + wm + mb * 32 + 8 * g + 4 * kh;
                float v4[4];
#pragma unroll
                for (int q = 0; q < 4; q++) {
                    float v = acc[mb][nb][4 * g + q] + bcol;
                    if (MODE == 1) {  // tanh-GELU == x * sigmoid(2u)
                        const float u2 = -1.5957691216057308f * (v + 0.044715f * v * v * v);
                        v = v * __builtin_amdgcn_rcpf(1.0f + __expf(u2));
                    }
                    v4[q] = v;
                }
                if (MODE == 2) {
#pragma unroll
                    for (int q = 0; q < 4; q++) {
                        const size_t idx = (size_t)(row0 + q) * N + col;
                        outf[idx] = v4[q] + resid[idx];
                    }
                } else if (MODE == 3 && col >= 2048) {
                    // V column -> vt[bh][d][s], 4 consecutive s per group
                    const int bh = (row0 >> 10) * 16 + ((col - 2048) >> 6);
                    const int d = (col - 2048) & 63;
                    bf16x4 pk;
#pragma unroll
                    for (int q = 0; q < 4; q++) pk[q] = (bf16_t)v4[q];
                    *(bf16x4*)(vt + (size_t)bh * 65536 + d * 1024 + (row0 & 1023)) = pk;
                } else {
#pragma unroll
                    for (int q = 0; q < 4; q++)
                        outb[(size_t)(row0 + q) * N + col] = (bf16_t)v4[q];
                }
            }
        }
    }
}

// ---------------------------------------------------------------- MFMA causal flash attention
// Grid (16 q-blocks, 128 bh), 256 thr = 4 waves; wave owns 16 queries.
// S^T = K @ Q^T (C: row=key, col=q=lane&15); O^T = V^T @ P^T (C: row=d, col=q).
__global__ __launch_bounds__(256) void attn_mfma(const bf16_t* __restrict__ qkv,
                                                 const bf16_t* __restrict__ vt,
                                                 bf16_t* __restrict__ o) {
    __shared__ bf16_t Ks[4096];       // [key=64][dseg swizzled]
    __shared__ bf16_t Vs[4096];       // [d=64][kseg swizzled]
    __shared__ bf16_t Ps[4][16][72];  // per-wave P[q][key], padded stride 72
    const int tid = threadIdx.x;
    const int w = tid >> 6;
    const int lane = tid & 63;
    const int l15 = lane & 15;
    const int quad = lane >> 4;
    const int qb = blockIdx.x;
    const int bh = blockIdx.y;
    const int b = bh >> 4, h = bh & 15;

    const int qrow = b * 1024 + qb * 64 + w * 16;
    const int qmaxw = qb * 64 + w * 16 + 15;

    bf16x8 qf[2];
#pragma unroll
    for (int f = 0; f < 2; f++) {
        bf16x8 t = *(const bf16x8*)(qkv + (size_t)(qrow + l15) * 3072 + h * 64 + f * 32 + quad * 8);
#pragma unroll
        for (int e = 0; e < 8; e++) t[e] = (bf16_t)((float)t[e] * 0.125f);
        qf[f] = t;
    }

    f32x4 Ot[4] = {};
    float mrow = -3.0e38f, lrow = 0.0f;

    const int c0 = w * 64 + lane;
    const int c1 = 256 + c0;
    const int r0 = c0 >> 3, g0 = (((c0 & 7) ^ (r0 & 7))) * 8;
    const int r1 = c1 >> 3, g1 = (((c1 & 7) ^ (r1 & 7))) * 8;

    const bf16_t* kbase = qkv + (size_t)(b * 1024) * 3072 + 1024 + h * 64;
    const bf16_t* vbase = vt + (size_t)bh * 64 * 1024;

    for (int kt = 0; kt <= qb; kt++) {
        async16(kbase + (size_t)(kt * 64 + r0) * 3072 + g0, Ks + w * 512);
        async16(kbase + (size_t)(kt * 64 + r1) * 3072 + g1, Ks + 2048 + w * 512);
        async16(vbase + (size_t)r0 * 1024 + kt * 64 + g0, Vs + w * 512);
        async16(vbase + (size_t)r1 * 1024 + kt * 64 + g1, Vs + 2048 + w * 512);
        __syncthreads();

        f32x4 sf[4];
#pragma unroll
        for (int kb = 0; kb < 4; kb++) {
            if (kt * 64 + kb * 16 > qmaxw) {
                sf[kb] = (f32x4){-3.0e38f, -3.0e38f, -3.0e38f, -3.0e38f};
                continue;
            }
            const int r = kb * 16 + l15;
            f32x4 acc = {};
#pragma unroll
            for (int f = 0; f < 2; f++) {
                const int seg = (f * 4 + quad) ^ (r & 7);
                const bf16x8 kf = *(const bf16x8*)(Ks + r * 64 + seg * 8);
                acc = __builtin_amdgcn_mfma_f32_16x16x32_bf16(kf, qf[f], acc, 0, 0, 0);
            }
            if (kt == qb && kb == w) {
#pragma unroll
                for (int rr2 = 0; rr2 < 4; rr2++)
                    if (quad * 4 + rr2 > l15) acc[rr2] = -3.0e38f;
            }
            sf[kb] = acc;
        }

        float tmax = -3.0e38f;
#pragma unroll
        for (int kb = 0; kb < 4; kb++)
#pragma unroll
            for (int rr2 = 0; rr2 < 4; rr2++) tmax = fmaxf(tmax, sf[kb][rr2]);
        tmax = fmaxf(tmax, __shfl_xor(tmax, 16));
        tmax = fmaxf(tmax, __shfl_xor(tmax, 32));
        const float mnew = fmaxf(mrow, tmax);
        const float alpha = __expf(mrow - mnew);
        float psum = 0.0f;
#pragma unroll
        for (int kb = 0; kb < 4; kb++) {
            bf16x4 pk;
#pragma unroll
            for (int rr2 = 0; rr2 < 4; rr2++) {
                const float p = __expf(sf[kb][rr2] - mnew);
                psum += p;
                pk[rr2] = (bf16_t)p;
            }
            *(bf16x4*)(&Ps[w][l15][kb * 16 + quad * 4]) = pk;
        }
        psum += __shfl_xor(psum, 16);
        psum += __shfl_xor(psum, 32);
        lrow = lrow * alpha + psum;
        mrow = mnew;
#pragma unroll
        for (int db = 0; db < 4; db++)
#pragma unroll
            for (int rr2 = 0; rr2 < 4; rr2++) Ot[db][rr2] *= alpha;

#pragma unroll
        for (int ks = 0; ks < 2; ks++) {
            if (kt * 64 + ks * 32 > qmaxw) break;
            const bf16x8 pf = *(const bf16x8*)(&Ps[w][l15][ks * 32 + quad * 8]);
#pragma unroll
            for (int db = 0; db < 4; db++) {
                const int d = db * 16 + l15;
                const int seg = (ks * 4 + quad) ^ (d & 7);
                const bf16x8 vf = *(const bf16x8*)(Vs + d * 64 + seg * 8);
                Ot[db] = __builtin_amdgcn_mfma_f32_16x16x32_bf16(vf, pf, Ot[db], 0, 0, 0);
            }
        }
        __syncthreads();
    }

    const float rl = 1.0f / lrow;
#pragma unroll
    for (int db = 0; db < 4; db++) {
        bf16x4 ov;
#pragma unroll
        for (int rr2 = 0; rr2 < 4; rr2++) ov[rr2] = (bf16_t)(Ot[db][rr2] * rl);
        *(bf16x4*)(o + (size_t)(qrow + l15) * 1024 + h * 64 + db * 16 + quad * 4) = ov;
    }
}

// ---------------------------------------------------------------- launch
extern "C" void kernel_launch(void* const* d_in, const int* in_sizes, int n_in,
                              void* d_out, int out_size, void* d_ws, size_t ws_size,
                              hipStream_t stream) {
    const float* x     = (const float*)d_in[0];
    const float* ln1g  = (const float*)d_in[1];
    const float* ln1b  = (const float*)d_in[2];
    const float* w_qkv = (const float*)d_in[3];
    const float* b_qkv = (const float*)d_in[4];
    const float* w_o   = (const float*)d_in[5];
    const float* b_o   = (const float*)d_in[6];
    const float* ln2g  = (const float*)d_in[7];
    const float* ln2b  = (const float*)d_in[8];
    const float* w1    = (const float*)d_in[9];
    const float* b1    = (const float*)d_in[10];
    const float* w2    = (const float*)d_in[11];
    const float* b2    = (const float*)d_in[12];
    float* out = (float*)d_out;

    char* w = (char*)d_ws;
    bf16_t* wbqkv = (bf16_t*)(w + 0);          //  6 MB  [3072,1024] bf16
    bf16_t* wbo   = (bf16_t*)(w + 6291456);    //  2 MB  [1024,1024]
    bf16_t* wb1   = (bf16_t*)(w + 8388608);    //  8 MB  [4096,1024]
    bf16_t* wb2   = (bf16_t*)(w + 16777216);   //  8 MB  [1024,4096]
    bf16_t* h     = (bf16_t*)(w + 25165824);   // 16 MB  [8192,1024] (LN1/LN2 out)
    bf16_t* qkv   = (bf16_t*)(w + 41943040);   // 48 MB  [8192,3072] (V region unused)
    bf16_t* ob    = (bf16_t*)(w + 92274688);   // 16 MB  [8192,1024]
    float*  x1    = (float*)(w + 109051904);   // 32 MB  [8192,1024] fp32
    bf16_t* f     = (bf16_t*)(w + 142606336);  // 64 MB  [8192,4096] (FFN1 out)
    bf16_t* vtb   = (bf16_t*)(w + 142606336);  // 16 MB  [128][64][1024] (aliases f; dead before FFN1)

    f2b_all<<<12288, 256, 0, stream>>>(w_qkv, w_o, w1, w2, wbqkv, wbo, wb1, wb2);

    ln_bf16<<<8192, 256, 0, stream>>>(x, ln1g, ln1b, h);
    gemm_bt<3><<<64 * 24, 256, 0, stream>>>(h, wbqkv, b_qkv, nullptr, qkv, nullptr, vtb, 3072, 1024);
    attn_mfma<<<dim3(16, 128), 256, 0, stream>>>(qkv, vtb, ob);
    gemm_bt<2><<<64 * 8, 256, 0, stream>>>(ob, wbo, b_o, x, nullptr, x1, nullptr, 1024, 1024);
    ln_bf16<<<8192, 256, 0, stream>>>(x1, ln2g, ln2b, h);
    gemm_bt<1><<<64 * 32, 256, 0, stream>>>(h, wb1, b1, nullptr, f, nullptr, nullptr, 4096, 1024);
    gemm_bt<2><<<64 * 8, 256, 0, stream>>>(f, wb2, b2, x1, nullptr, out, nullptr, 1024, 4096);
}

// Round 5
// 477.812 us; speedup vs baseline: 1.0593x; 1.0593x over previous
//
#include <hip/hip_runtime.h>
#include <math.h>

// CLIP transformer layer: B=8 S=1024 D=1024 H=16 DH=64 FF=4096, fp32 I/O,
// bf16 MFMA internals. Round 5: revert GEMM inner to conflict-free 16x16x32
// fragment pattern (round-3, measured 0 conflicts); keep sigmoid-GELU,
// fused V-transpose, merged weight converts from round 4.

typedef __bf16 bf16_t;
typedef __bf16 bf16x4 __attribute__((ext_vector_type(4)));
typedef __bf16 bf16x8 __attribute__((ext_vector_type(8)));
typedef float f32x4 __attribute__((ext_vector_type(4)));

// ---------------------------------------------------------------- helpers
__device__ __forceinline__ void async16(const void* g, void* l) {
    // global -> LDS direct DMA, 16B/lane. LDS dest is wave-uniform base + lane*16.
    __builtin_amdgcn_global_load_lds(
        (const __attribute__((address_space(1))) void*)g,
        (__attribute__((address_space(3))) void*)l,
        16, 0, 0);
}

// ---------------------------------------------------------------- fp32 -> bf16 convert (all 4 weights, one dispatch)
__global__ __launch_bounds__(256) void f2b_all(
    const float* __restrict__ s0, const float* __restrict__ s1,
    const float* __restrict__ s2, const float* __restrict__ s3,
    bf16_t* __restrict__ d0, bf16_t* __restrict__ d1,
    bf16_t* __restrict__ d2, bf16_t* __restrict__ d3) {
    const int g = blockIdx.x * 256 + threadIdx.x;  // float4-group index
    const float* s;
    bf16_t* d;
    int off;
    if (g < 786432)       { s = s0; d = d0; off = g; }            // w_qkv 3M elem
    else if (g < 1048576) { s = s1; d = d1; off = g - 786432; }   // w_o 1M
    else if (g < 2097152) { s = s2; d = d2; off = g - 1048576; }  // w1 4M
    else                  { s = s3; d = d3; off = g - 2097152; }  // w2 4M
    const int i = off * 4;
    const float4 v = *(const float4*)(s + i);
    bf16x4 o;
    o[0] = (bf16_t)v.x; o[1] = (bf16_t)v.y; o[2] = (bf16_t)v.z; o[3] = (bf16_t)v.w;
    *(bf16x4*)(d + i) = o;
}

// ---------------------------------------------------------------- LayerNorm (row of 1024) -> bf16
__global__ __launch_bounds__(256) void ln_bf16(const float* __restrict__ x,
                                               const float* __restrict__ g,
                                               const float* __restrict__ bb,
                                               bf16_t* __restrict__ out) {
    const int tid = threadIdx.x;
    const int row = blockIdx.x;
    const float4 xv = *(const float4*)(x + row * 1024 + tid * 4);
    float s1 = xv.x + xv.y + xv.z + xv.w;
    float s2 = xv.x * xv.x + xv.y * xv.y + xv.z * xv.z + xv.w * xv.w;
#pragma unroll
    for (int m = 32; m >= 1; m >>= 1) {
        s1 += __shfl_xor(s1, m);
        s2 += __shfl_xor(s2, m);
    }
    __shared__ float r1[4], r2[4];
    const int wid = tid >> 6, lane = tid & 63;
    if (lane == 0) { r1[wid] = s1; r2[wid] = s2; }
    __syncthreads();
    s1 = r1[0] + r1[1] + r1[2] + r1[3];
    s2 = r2[0] + r2[1] + r2[2] + r2[3];
    const float mu = s1 * (1.0f / 1024.0f);
    const float var = s2 * (1.0f / 1024.0f) - mu * mu;
    const float rs = rsqrtf(var + 1e-5f);
    const float4 gv = *(const float4*)(g + tid * 4);
    const float4 bv = *(const float4*)(bb + tid * 4);
    bf16x4 o;
    o[0] = (bf16_t)((xv.x - mu) * rs * gv.x + bv.x);
    o[1] = (bf16_t)((xv.y - mu) * rs * gv.y + bv.y);
    o[2] = (bf16_t)((xv.z - mu) * rs * gv.z + bv.z);
    o[3] = (bf16_t)((xv.w - mu) * rs * gv.w + bv.w);
    *(bf16x4*)(out + row * 1024 + tid * 4) = o;
}

// ---------------------------------------------------------------- GEMM: C[M,N] = A[M,K] @ W[N,K]^T + bias
// 128x128 tile, BK=64, XOR-swizzled LDS (conflict-free b128 frag reads),
// 4x4 of 16x16x32 MFMA per wave (measured 0 bank conflicts).
// MODE 0: bias -> bf16; MODE 1: bias+gelu(sigmoid form) -> bf16;
// MODE 2: bias+residual -> fp32; MODE 3: QKV (bias -> bf16 for Q/K cols,
//         V cols transposed straight into vt[bh][d][s]).
template <int MODE>
__global__ __launch_bounds__(256, 2) void gemm_bt(
    const bf16_t* __restrict__ A, const bf16_t* __restrict__ W,
    const float* __restrict__ bias, const float* __restrict__ resid,
    bf16_t* __restrict__ outb, float* __restrict__ outf,
    bf16_t* __restrict__ vt, int N, int K) {
    __shared__ bf16_t As[128 * 64];
    __shared__ bf16_t Bs[128 * 64];
    const int tid = threadIdx.x;
    const int w = tid >> 6;
    const int lane = tid & 63;
    const int l15 = lane & 15;
    const int quad = lane >> 4;

    // block swizzle: groups of 8 m-blocks share the n-column (W-tile reuse)
    const int nbn = N >> 7;
    const int per = 8 * nbn;
    const int lid = blockIdx.x;
    const int bm = (lid / per) * 8 + (lid % per) % 8;
    const int bn = (lid % per) / 8;
    const int m0 = bm * 128;
    const int n0 = bn * 128;
    const int wm = (w & 1) * 64;
    const int wn = (w >> 1) * 64;

    // staging: 4 calls/wave per operand; chunk c = q*256 + w*64 + lane (16B each).
    // LDS slot (row r, seg s) holds global k-seg (s ^ (r&7)).
    int rr[4], so[4];
#pragma unroll
    for (int q = 0; q < 4; q++) {
        const int c = q * 256 + w * 64 + lane;
        rr[q] = c >> 3;
        so[q] = ((c & 7) ^ (rr[q] & 7)) * 8;
    }
    const bf16_t* pA[4];
    const bf16_t* pB[4];
#pragma unroll
    for (int q = 0; q < 4; q++) {
        pA[q] = A + (size_t)(m0 + rr[q]) * K + so[q];
        pB[q] = W + (size_t)(n0 + rr[q]) * K + so[q];
    }

    f32x4 acc[4][4] = {};

    for (int k0 = 0; k0 < K; k0 += 64) {
#pragma unroll
        for (int q = 0; q < 4; q++) {
            async16(pA[q], As + q * 2048 + w * 512);
            async16(pB[q], Bs + q * 2048 + w * 512);
            pA[q] += 64; pB[q] += 64;
        }
        __syncthreads();  // drains vmcnt -> LDS tiles visible

        // fragments: A[m = l15][k = quad*8+j] per 32-k-step; swizzled slot lookup
        bf16x8 af[4][2], bfr[4][2];
#pragma unroll
        for (int i = 0; i < 4; i++) {
            const int r = wm + i * 16 + l15;
#pragma unroll
            for (int f = 0; f < 2; f++) {
                const int slot = (f * 4 + quad) ^ (r & 7);
                af[i][f] = *(const bf16x8*)(As + r * 64 + slot * 8);
            }
        }
#pragma unroll
        for (int j = 0; j < 4; j++) {
            const int r = wn + j * 16 + l15;
#pragma unroll
            for (int f = 0; f < 2; f++) {
                const int slot = (f * 4 + quad) ^ (r & 7);
                bfr[j][f] = *(const bf16x8*)(Bs + r * 64 + slot * 8);
            }
        }
#pragma unroll
        for (int i = 0; i < 4; i++)
#pragma unroll
            for (int j = 0; j < 4; j++)
#pragma unroll
                for (int f = 0; f < 2; f++)
                    acc[i][j] = __builtin_amdgcn_mfma_f32_16x16x32_bf16(
                        af[i][f], bfr[j][f], acc[i][j], 0, 0, 0);
        __syncthreads();  // protect LDS from next iteration's staging
    }

    // epilogue: C/D layout col=lane&15 (n), row=(lane>>4)*4+reg (m)
#pragma unroll
    for (int i = 0; i < 4; i++) {
#pragma unroll
        for (int j = 0; j < 4; j++) {
            const int col = n0 + wn + j * 16 + l15;
            const float bcol = bias[col];
            const int row0 = m0 + wm + i * 16 + quad * 4;
            float v4[4];
#pragma unroll
            for (int q = 0; q < 4; q++) {
                float v = acc[i][j][q] + bcol;
                if (MODE == 1) {  // tanh-GELU == x * sigmoid(2u)
                    const float u2 = -1.5957691216057308f * (v + 0.044715f * v * v * v);
                    v = v * __builtin_amdgcn_rcpf(1.0f + __expf(u2));
                }
                v4[q] = v;
            }
            if (MODE == 2) {
#pragma unroll
                for (int q = 0; q < 4; q++) {
                    const size_t idx = (size_t)(row0 + q) * N + col;
                    outf[idx] = v4[q] + resid[idx];
                }
            } else if (MODE == 3 && col >= 2048) {
                // V column -> vt[bh][d][s]; regs q = 4 consecutive s
                const int bh = (row0 >> 10) * 16 + ((col - 2048) >> 6);
                const int d = (col - 2048) & 63;
                bf16x4 pk;
#pragma unroll
                for (int q = 0; q < 4; q++) pk[q] = (bf16_t)v4[q];
                *(bf16x4*)(vt + (size_t)bh * 65536 + d * 1024 + (row0 & 1023)) = pk;
            } else {
#pragma unroll
                for (int q = 0; q < 4; q++)
                    outb[(size_t)(row0 + q) * N + col] = (bf16_t)v4[q];
            }
        }
    }
}

// ---------------------------------------------------------------- MFMA causal flash attention
// Grid (16 q-blocks, 128 bh), 256 thr = 4 waves; wave owns 16 queries.
// S^T = K @ Q^T (C: row=key, col=q=lane&15); O^T = V^T @ P^T (C: row=d, col=q).
__global__ __launch_bounds__(256) void attn_mfma(const bf16_t* __restrict__ qkv,
                                                 const bf16_t* __restrict__ vt,
                                                 bf16_t* __restrict__ o) {
    __shared__ bf16_t Ks[4096];       // [key=64][dseg swizzled]
    __shared__ bf16_t Vs[4096];       // [d=64][kseg swizzled]
    __shared__ bf16_t Ps[4][16][72];  // per-wave P[q][key], padded stride 72
    const int tid = threadIdx.x;
    const int w = tid >> 6;
    const int lane = tid & 63;
    const int l15 = lane & 15;
    const int quad = lane >> 4;
    const int qb = blockIdx.x;
    const int bh = blockIdx.y;
    const int b = bh >> 4, h = bh & 15;

    const int qrow = b * 1024 + qb * 64 + w * 16;
    const int qmaxw = qb * 64 + w * 16 + 15;

    bf16x8 qf[2];
#pragma unroll
    for (int f = 0; f < 2; f++) {
        bf16x8 t = *(const bf16x8*)(qkv + (size_t)(qrow + l15) * 3072 + h * 64 + f * 32 + quad * 8);
#pragma unroll
        for (int e = 0; e < 8; e++) t[e] = (bf16_t)((float)t[e] * 0.125f);
        qf[f] = t;
    }

    f32x4 Ot[4] = {};
    float mrow = -3.0e38f, lrow = 0.0f;

    const int c0 = w * 64 + lane;
    const int c1 = 256 + c0;
    const int r0 = c0 >> 3, g0 = (((c0 & 7) ^ (r0 & 7))) * 8;
    const int r1 = c1 >> 3, g1 = (((c1 & 7) ^ (r1 & 7))) * 8;

    const bf16_t* kbase = qkv + (size_t)(b * 1024) * 3072 + 1024 + h * 64;
    const bf16_t* vbase = vt + (size_t)bh * 64 * 1024;

    for (int kt = 0; kt <= qb; kt++) {
        async16(kbase + (size_t)(kt * 64 + r0) * 3072 + g0, Ks + w * 512);
        async16(kbase + (size_t)(kt * 64 + r1) * 3072 + g1, Ks + 2048 + w * 512);
        async16(vbase + (size_t)r0 * 1024 + kt * 64 + g0, Vs + w * 512);
        async16(vbase + (size_t)r1 * 1024 + kt * 64 + g1, Vs + 2048 + w * 512);
        __syncthreads();

        f32x4 sf[4];
#pragma unroll
        for (int kb = 0; kb < 4; kb++) {
            if (kt * 64 + kb * 16 > qmaxw) {
                sf[kb] = (f32x4){-3.0e38f, -3.0e38f, -3.0e38f, -3.0e38f};
                continue;
            }
            const int r = kb * 16 + l15;
            f32x4 acc = {};
#pragma unroll
            for (int f = 0; f < 2; f++) {
                const int seg = (f * 4 + quad) ^ (r & 7);
                const bf16x8 kf = *(const bf16x8*)(Ks + r * 64 + seg * 8);
                acc = __builtin_amdgcn_mfma_f32_16x16x32_bf16(kf, qf[f], acc, 0, 0, 0);
            }
            if (kt == qb && kb == w) {
#pragma unroll
                for (int rr2 = 0; rr2 < 4; rr2++)
                    if (quad * 4 + rr2 > l15) acc[rr2] = -3.0e38f;
            }
            sf[kb] = acc;
        }

        float tmax = -3.0e38f;
#pragma unroll
        for (int kb = 0; kb < 4; kb++)
#pragma unroll
            for (int rr2 = 0; rr2 < 4; rr2++) tmax = fmaxf(tmax, sf[kb][rr2]);
        tmax = fmaxf(tmax, __shfl_xor(tmax, 16));
        tmax = fmaxf(tmax, __shfl_xor(tmax, 32));
        const float mnew = fmaxf(mrow, tmax);
        const float alpha = __expf(mrow - mnew);
        float psum = 0.0f;
#pragma unroll
        for (int kb = 0; kb < 4; kb++) {
            bf16x4 pk;
#pragma unroll
            for (int rr2 = 0; rr2 < 4; rr2++) {
                const float p = __expf(sf[kb][rr2] - mnew);
                psum += p;
                pk[rr2] = (bf16_t)p;
            }
            *(bf16x4*)(&Ps[w][l15][kb * 16 + quad * 4]) = pk;
        }
        psum += __shfl_xor(psum, 16);
        psum += __shfl_xor(psum, 32);
        lrow = lrow * alpha + psum;
        mrow = mnew;
#pragma unroll
        for (int db = 0; db < 4; db++)
#pragma unroll
            for (int rr2 = 0; rr2 < 4; rr2++) Ot[db][rr2] *= alpha;

#pragma unroll
        for (int ks = 0; ks < 2; ks++) {
            if (kt * 64 + ks * 32 > qmaxw) break;
            const bf16x8 pf = *(const bf16x8*)(&Ps[w][l15][ks * 32 + quad * 8]);
#pragma unroll
            for (int db = 0; db < 4; db++) {
                const int d = db * 16 + l15;
                const int seg = (ks * 4 + quad) ^ (d & 7);
                const bf16x8 vf = *(const bf16x8*)(Vs + d * 64 + seg * 8);
                Ot[db] = __builtin_amdgcn_mfma_f32_16x16x32_bf16(vf, pf, Ot[db], 0, 0, 0);
            }
        }
        __syncthreads();
    }

    const float rl = 1.0f / lrow;
#pragma unroll
    for (int db = 0; db < 4; db++) {
        bf16x4 ov;
#pragma unroll
        for (int rr2 = 0; rr2 < 4; rr2++) ov[rr2] = (bf16_t)(Ot[db][rr2] * rl);
        *(bf16x4*)(o + (size_t)(qrow + l15) * 1024 + h * 64 + db * 16 + quad * 4) = ov;
    }
}

// ---------------------------------------------------------------- launch
extern "C" void kernel_launch(void* const* d_in, const int* in_sizes, int n_in,
                              void* d_out, int out_size, void* d_ws, size_t ws_size,
                              hipStream_t stream) {
    const float* x     = (const float*)d_in[0];
    const float* ln1g  = (const float*)d_in[1];
    const float* ln1b  = (const float*)d_in[2];
    const float* w_qkv = (const float*)d_in[3];
    const float* b_qkv = (const float*)d_in[4];
    const float* w_o   = (const float*)d_in[5];
    const float* b_o   = (const float*)d_in[6];
    const float* ln2g  = (const float*)d_in[7];
    const float* ln2b  = (const float*)d_in[8];
    const float* w1    = (const float*)d_in[9];
    const float* b1    = (const float*)d_in[10];
    const float* w2    = (const float*)d_in[11];
    const float* b2    = (const float*)d_in[12];
    float* out = (float*)d_out;

    char* w = (char*)d_ws;
    bf16_t* wbqkv = (bf16_t*)(w + 0);          //  6 MB  [3072,1024] bf16
    bf16_t* wbo   = (bf16_t*)(w + 6291456);    //  2 MB  [1024,1024]
    bf16_t* wb1   = (bf16_t*)(w + 8388608);    //  8 MB  [4096,1024]
    bf16_t* wb2   = (bf16_t*)(w + 16777216);   //  8 MB  [1024,4096]
    bf16_t* h     = (bf16_t*)(w + 25165824);   // 16 MB  [8192,1024] (LN1/LN2 out)
    bf16_t* qkv   = (bf16_t*)(w + 41943040);   // 48 MB  [8192,3072] (V region unused)
    bf16_t* ob    = (bf16_t*)(w + 92274688);   // 16 MB  [8192,1024]
    float*  x1    = (float*)(w + 109051904);   // 32 MB  [8192,1024] fp32
    bf16_t* f     = (bf16_t*)(w + 142606336);  // 64 MB  [8192,4096] (FFN1 out)
    bf16_t* vtb   = (bf16_t*)(w + 142606336);  // 16 MB  [128][64][1024] (aliases f; dead before FFN1)

    f2b_all<<<12288, 256, 0, stream>>>(w_qkv, w_o, w1, w2, wbqkv, wbo, wb1, wb2);

    ln_bf16<<<8192, 256, 0, stream>>>(x, ln1g, ln1b, h);
    gemm_bt<3><<<64 * 24, 256, 0, stream>>>(h, wbqkv, b_qkv, nullptr, qkv, nullptr, vtb, 3072, 1024);
    attn_mfma<<<dim3(16, 128), 256, 0, stream>>>(qkv, vtb, ob);
    gemm_bt<2><<<64 * 8, 256, 0, stream>>>(ob, wbo, b_o, x, nullptr, x1, nullptr, 1024, 1024);
    ln_bf16<<<8192, 256, 0, stream>>>(x1, ln2g, ln2b, h);
    gemm_bt<1><<<64 * 32, 256, 0, stream>>>(h, wb1, b1, nullptr, f, nullptr, nullptr, 4096, 1024);
    gemm_bt<2><<<64 * 8, 256, 0, stream>>>(f, wb2, b2, x1, nullptr, out, nullptr, 1024, 4096);
}

// Round 6
// 471.382 us; speedup vs baseline: 1.0738x; 1.0136x over previous
//
#include <hip/hip_runtime.h>
#include <math.h>

// CLIP transformer layer: B=8 S=1024 D=1024 H=16 DH=64 FF=4096, fp32 I/O,
// bf16 MFMA internals. Round 6: attention 128q/block (8 waves, 512 thr,
// half the barriers+staging per query); f2b+LN1 fused into one prep dispatch.

typedef __bf16 bf16_t;
typedef __bf16 bf16x4 __attribute__((ext_vector_type(4)));
typedef __bf16 bf16x8 __attribute__((ext_vector_type(8)));
typedef float f32x4 __attribute__((ext_vector_type(4)));

// ---------------------------------------------------------------- helpers
__device__ __forceinline__ void async16(const void* g, void* l) {
    // global -> LDS direct DMA, 16B/lane. LDS dest is wave-uniform base + lane*16.
    __builtin_amdgcn_global_load_lds(
        (const __attribute__((address_space(1))) void*)g,
        (__attribute__((address_space(3))) void*)l,
        16, 0, 0);
}

__device__ __forceinline__ void ln_row(const float* __restrict__ x,
                                       const float* __restrict__ g,
                                       const float* __restrict__ bb,
                                       bf16_t* __restrict__ out, int row) {
    const int tid = threadIdx.x;
    const float4 xv = *(const float4*)(x + row * 1024 + tid * 4);
    float s1 = xv.x + xv.y + xv.z + xv.w;
    float s2 = xv.x * xv.x + xv.y * xv.y + xv.z * xv.z + xv.w * xv.w;
#pragma unroll
    for (int m = 32; m >= 1; m >>= 1) {
        s1 += __shfl_xor(s1, m);
        s2 += __shfl_xor(s2, m);
    }
    __shared__ float r1[4], r2[4];
    const int wid = tid >> 6, lane = tid & 63;
    if (lane == 0) { r1[wid] = s1; r2[wid] = s2; }
    __syncthreads();
    s1 = r1[0] + r1[1] + r1[2] + r1[3];
    s2 = r2[0] + r2[1] + r2[2] + r2[3];
    const float mu = s1 * (1.0f / 1024.0f);
    const float var = s2 * (1.0f / 1024.0f) - mu * mu;
    const float rs = rsqrtf(var + 1e-5f);
    const float4 gv = *(const float4*)(g + tid * 4);
    const float4 bv = *(const float4*)(bb + tid * 4);
    bf16x4 o;
    o[0] = (bf16_t)((xv.x - mu) * rs * gv.x + bv.x);
    o[1] = (bf16_t)((xv.y - mu) * rs * gv.y + bv.y);
    o[2] = (bf16_t)((xv.z - mu) * rs * gv.z + bv.z);
    o[3] = (bf16_t)((xv.w - mu) * rs * gv.w + bv.w);
    *(bf16x4*)(out + row * 1024 + tid * 4) = o;
}

// ---------------------------------------------------------------- prep: weight converts (blocks 0..12287) + LN1 (blocks 12288..20479)
__global__ __launch_bounds__(256) void prep(
    const float* __restrict__ s0, const float* __restrict__ s1,
    const float* __restrict__ s2, const float* __restrict__ s3,
    bf16_t* __restrict__ d0, bf16_t* __restrict__ d1,
    bf16_t* __restrict__ d2, bf16_t* __restrict__ d3,
    const float* __restrict__ x, const float* __restrict__ ln1g,
    const float* __restrict__ ln1b, bf16_t* __restrict__ h) {
    if (blockIdx.x >= 12288) {
        ln_row(x, ln1g, ln1b, h, blockIdx.x - 12288);
        return;
    }
    const int g = blockIdx.x * 256 + threadIdx.x;  // float4-group index
    const float* s;
    bf16_t* d;
    int off;
    if (g < 786432)       { s = s0; d = d0; off = g; }            // w_qkv 3M elem
    else if (g < 1048576) { s = s1; d = d1; off = g - 786432; }   // w_o 1M
    else if (g < 2097152) { s = s2; d = d2; off = g - 1048576; }  // w1 4M
    else                  { s = s3; d = d3; off = g - 2097152; }  // w2 4M
    const int i = off * 4;
    const float4 v = *(const float4*)(s + i);
    bf16x4 o;
    o[0] = (bf16_t)v.x; o[1] = (bf16_t)v.y; o[2] = (bf16_t)v.z; o[3] = (bf16_t)v.w;
    *(bf16x4*)(d + i) = o;
}

// ---------------------------------------------------------------- LayerNorm (row of 1024) -> bf16
__global__ __launch_bounds__(256) void ln_bf16(const float* __restrict__ x,
                                               const float* __restrict__ g,
                                               const float* __restrict__ bb,
                                               bf16_t* __restrict__ out) {
    ln_row(x, g, bb, out, blockIdx.x);
}

// ---------------------------------------------------------------- GEMM: C[M,N] = A[M,K] @ W[N,K]^T + bias
// 128x128 tile, BK=64, XOR-swizzled LDS (conflict-free b128 frag reads),
// 4x4 of 16x16x32 MFMA per wave (measured 0 bank conflicts).
// MODE 0: bias -> bf16; MODE 1: bias+gelu(sigmoid form) -> bf16;
// MODE 2: bias+residual -> fp32; MODE 3: QKV (bias -> bf16 for Q/K cols,
//         V cols transposed straight into vt[bh][d][s]).
template <int MODE>
__global__ __launch_bounds__(256, 2) void gemm_bt(
    const bf16_t* __restrict__ A, const bf16_t* __restrict__ W,
    const float* __restrict__ bias, const float* __restrict__ resid,
    bf16_t* __restrict__ outb, float* __restrict__ outf,
    bf16_t* __restrict__ vt, int N, int K) {
    __shared__ bf16_t As[128 * 64];
    __shared__ bf16_t Bs[128 * 64];
    const int tid = threadIdx.x;
    const int w = tid >> 6;
    const int lane = tid & 63;
    const int l15 = lane & 15;
    const int quad = lane >> 4;

    // block swizzle: groups of 8 m-blocks share the n-column (W-tile reuse)
    const int nbn = N >> 7;
    const int per = 8 * nbn;
    const int lid = blockIdx.x;
    const int bm = (lid / per) * 8 + (lid % per) % 8;
    const int bn = (lid % per) / 8;
    const int m0 = bm * 128;
    const int n0 = bn * 128;
    const int wm = (w & 1) * 64;
    const int wn = (w >> 1) * 64;

    // staging: 4 calls/wave per operand; chunk c = q*256 + w*64 + lane (16B each).
    // LDS slot (row r, seg s) holds global k-seg (s ^ (r&7)).
    int rr[4], so[4];
#pragma unroll
    for (int q = 0; q < 4; q++) {
        const int c = q * 256 + w * 64 + lane;
        rr[q] = c >> 3;
        so[q] = ((c & 7) ^ (rr[q] & 7)) * 8;
    }
    const bf16_t* pA[4];
    const bf16_t* pB[4];
#pragma unroll
    for (int q = 0; q < 4; q++) {
        pA[q] = A + (size_t)(m0 + rr[q]) * K + so[q];
        pB[q] = W + (size_t)(n0 + rr[q]) * K + so[q];
    }

    f32x4 acc[4][4] = {};

    for (int k0 = 0; k0 < K; k0 += 64) {
#pragma unroll
        for (int q = 0; q < 4; q++) {
            async16(pA[q], As + q * 2048 + w * 512);
            async16(pB[q], Bs + q * 2048 + w * 512);
            pA[q] += 64; pB[q] += 64;
        }
        __syncthreads();  // drains vmcnt -> LDS tiles visible

        bf16x8 af[4][2], bfr[4][2];
#pragma unroll
        for (int i = 0; i < 4; i++) {
            const int r = wm + i * 16 + l15;
#pragma unroll
            for (int f = 0; f < 2; f++) {
                const int slot = (f * 4 + quad) ^ (r & 7);
                af[i][f] = *(const bf16x8*)(As + r * 64 + slot * 8);
            }
        }
#pragma unroll
        for (int j = 0; j < 4; j++) {
            const int r = wn + j * 16 + l15;
#pragma unroll
            for (int f = 0; f < 2; f++) {
                const int slot = (f * 4 + quad) ^ (r & 7);
                bfr[j][f] = *(const bf16x8*)(Bs + r * 64 + slot * 8);
            }
        }
#pragma unroll
        for (int i = 0; i < 4; i++)
#pragma unroll
            for (int j = 0; j < 4; j++)
#pragma unroll
                for (int f = 0; f < 2; f++)
                    acc[i][j] = __builtin_amdgcn_mfma_f32_16x16x32_bf16(
                        af[i][f], bfr[j][f], acc[i][j], 0, 0, 0);
        __syncthreads();  // protect LDS from next iteration's staging
    }

    // epilogue: C/D layout col=lane&15 (n), row=(lane>>4)*4+reg (m)
#pragma unroll
    for (int i = 0; i < 4; i++) {
#pragma unroll
        for (int j = 0; j < 4; j++) {
            const int col = n0 + wn + j * 16 + l15;
            const float bcol = bias[col];
            const int row0 = m0 + wm + i * 16 + quad * 4;
            float v4[4];
#pragma unroll
            for (int q = 0; q < 4; q++) {
                float v = acc[i][j][q] + bcol;
                if (MODE == 1) {  // tanh-GELU == x * sigmoid(2u)
                    const float u2 = -1.5957691216057308f * (v + 0.044715f * v * v * v);
                    v = v * __builtin_amdgcn_rcpf(1.0f + __expf(u2));
                }
                v4[q] = v;
            }
            if (MODE == 2) {
#pragma unroll
                for (int q = 0; q < 4; q++) {
                    const size_t idx = (size_t)(row0 + q) * N + col;
                    outf[idx] = v4[q] + resid[idx];
                }
            } else if (MODE == 3 && col >= 2048) {
                // V column -> vt[bh][d][s]; regs q = 4 consecutive s
                const int bh = (row0 >> 10) * 16 + ((col - 2048) >> 6);
                const int d = (col - 2048) & 63;
                bf16x4 pk;
#pragma unroll
                for (int q = 0; q < 4; q++) pk[q] = (bf16_t)v4[q];
                *(bf16x4*)(vt + (size_t)bh * 65536 + d * 1024 + (row0 & 1023)) = pk;
            } else {
#pragma unroll
                for (int q = 0; q < 4; q++)
                    outb[(size_t)(row0 + q) * N + col] = (bf16_t)v4[q];
            }
        }
    }
}

// ---------------------------------------------------------------- MFMA causal flash attention
// Grid (8 q-blocks of 128, 128 bh), 512 thr = 8 waves; wave owns 16 queries.
// S^T = K @ Q^T (C: row=key, col=q=lane&15); O^T = V^T @ P^T (C: row=d, col=q).
// K/V staged once per 64-key tile for all 128 queries (half the staging and
// barriers per query vs 64-q blocks).
__global__ __launch_bounds__(512) void attn_mfma(const bf16_t* __restrict__ qkv,
                                                 const bf16_t* __restrict__ vt,
                                                 bf16_t* __restrict__ o) {
    __shared__ bf16_t Ks[4096];       // [key=64][dseg swizzled]  8KB
    __shared__ bf16_t Vs[4096];       // [d=64][kseg swizzled]    8KB
    __shared__ bf16_t Ps[8][16][72];  // per-wave P[q][key], padded stride 72 (18KB)
    const int tid = threadIdx.x;
    const int w = tid >> 6;           // 0..7
    const int lane = tid & 63;
    const int l15 = lane & 15;
    const int quad = lane >> 4;
    const int qb = blockIdx.x;        // q-block of 128
    const int bh = blockIdx.y;
    const int b = bh >> 4, h = bh & 15;

    const int qrow = b * 1024 + qb * 128 + w * 16;  // wave's first query row (global)
    const int qmaxw = qb * 128 + w * 16 + 15;       // wave's max query (in-seq)
    const int ktd = qmaxw >> 6;                     // wave's diagonal tile
    const int kbd = w & 3;                          // diagonal 16-block within tile

    // Q^T B-frags: lane holds Q[q=l15][d=f*32+quad*8+j], scaled by 1/8
    bf16x8 qf[2];
#pragma unroll
    for (int f = 0; f < 2; f++) {
        bf16x8 t = *(const bf16x8*)(qkv + (size_t)(qrow + l15) * 3072 + h * 64 + f * 32 + quad * 8);
#pragma unroll
        for (int e = 0; e < 8; e++) t[e] = (bf16_t)((float)t[e] * 0.125f);
        qf[f] = t;
    }

    f32x4 Ot[4] = {};
    float mrow = -3.0e38f, lrow = 0.0f;

    // staging: 1 call/wave per operand; chunk c = w*64 + lane (16B each)
    const int c0 = w * 64 + lane;
    const int r0 = c0 >> 3, g0 = (((c0 & 7) ^ (r0 & 7))) * 8;

    const bf16_t* kbase = qkv + (size_t)(b * 1024) * 3072 + 1024 + h * 64;
    const bf16_t* vbase = vt + (size_t)bh * 64 * 1024;

    const int ktmax = 2 * qb + 1;  // keys up to qb*128+127
    for (int kt = 0; kt <= ktmax; kt++) {
        async16(kbase + (size_t)(kt * 64 + r0) * 3072 + g0, Ks + w * 512);
        async16(vbase + (size_t)r0 * 1024 + kt * 64 + g0, Vs + w * 512);
        __syncthreads();

        f32x4 sf[4];
#pragma unroll
        for (int kb = 0; kb < 4; kb++) {
            if (kt * 64 + kb * 16 > qmaxw) {  // fully masked key-block (wave-uniform)
                sf[kb] = (f32x4){-3.0e38f, -3.0e38f, -3.0e38f, -3.0e38f};
                continue;
            }
            const int r = kb * 16 + l15;
            f32x4 acc = {};
#pragma unroll
            for (int f = 0; f < 2; f++) {
                const int seg = (f * 4 + quad) ^ (r & 7);
                const bf16x8 kf = *(const bf16x8*)(Ks + r * 64 + seg * 8);
                acc = __builtin_amdgcn_mfma_f32_16x16x32_bf16(kf, qf[f], acc, 0, 0, 0);
            }
            if (kt == ktd && kb == kbd) {  // diagonal 16-block: per-element mask
#pragma unroll
                for (int rr2 = 0; rr2 < 4; rr2++)
                    if (quad * 4 + rr2 > l15) acc[rr2] = -3.0e38f;
            }
            sf[kb] = acc;
        }

        // online softmax over columns (q = l15): in-lane 16 + shuffle over quads
        float tmax = -3.0e38f;
#pragma unroll
        for (int kb = 0; kb < 4; kb++)
#pragma unroll
            for (int rr2 = 0; rr2 < 4; rr2++) tmax = fmaxf(tmax, sf[kb][rr2]);
        tmax = fmaxf(tmax, __shfl_xor(tmax, 16));
        tmax = fmaxf(tmax, __shfl_xor(tmax, 32));
        const float mnew = fmaxf(mrow, tmax);
        const float alpha = __expf(mrow - mnew);
        float psum = 0.0f;
#pragma unroll
        for (int kb = 0; kb < 4; kb++) {
            bf16x4 pk;
#pragma unroll
            for (int rr2 = 0; rr2 < 4; rr2++) {
                const float p = __expf(sf[kb][rr2] - mnew);
                psum += p;
                pk[rr2] = (bf16_t)p;
            }
            *(bf16x4*)(&Ps[w][l15][kb * 16 + quad * 4]) = pk;
        }
        psum += __shfl_xor(psum, 16);
        psum += __shfl_xor(psum, 32);
        lrow = lrow * alpha + psum;
        mrow = mnew;
#pragma unroll
        for (int db = 0; db < 4; db++)
#pragma unroll
            for (int rr2 = 0; rr2 < 4; rr2++) Ot[db][rr2] *= alpha;

#pragma unroll
        for (int ks = 0; ks < 2; ks++) {
            if (kt * 64 + ks * 32 > qmaxw) break;  // all-zero P (wave-uniform)
            const bf16x8 pf = *(const bf16x8*)(&Ps[w][l15][ks * 32 + quad * 8]);
#pragma unroll
            for (int db = 0; db < 4; db++) {
                const int d = db * 16 + l15;
                const int seg = (ks * 4 + quad) ^ (d & 7);
                const bf16x8 vf = *(const bf16x8*)(Vs + d * 64 + seg * 8);
                Ot[db] = __builtin_amdgcn_mfma_f32_16x16x32_bf16(vf, pf, Ot[db], 0, 0, 0);
            }
        }
        __syncthreads();  // protect Ks/Vs before next staging
    }

    const float rl = 1.0f / lrow;
#pragma unroll
    for (int db = 0; db < 4; db++) {
        bf16x4 ov;
#pragma unroll
        for (int rr2 = 0; rr2 < 4; rr2++) ov[rr2] = (bf16_t)(Ot[db][rr2] * rl);
        *(bf16x4*)(o + (size_t)(qrow + l15) * 1024 + h * 64 + db * 16 + quad * 4) = ov;
    }
}

// ---------------------------------------------------------------- launch
extern "C" void kernel_launch(void* const* d_in, const int* in_sizes, int n_in,
                              void* d_out, int out_size, void* d_ws, size_t ws_size,
                              hipStream_t stream) {
    const float* x     = (const float*)d_in[0];
    const float* ln1g  = (const float*)d_in[1];
    const float* ln1b  = (const float*)d_in[2];
    const float* w_qkv = (const float*)d_in[3];
    const float* b_qkv = (const float*)d_in[4];
    const float* w_o   = (const float*)d_in[5];
    const float* b_o   = (const float*)d_in[6];
    const float* ln2g  = (const float*)d_in[7];
    const float* ln2b  = (const float*)d_in[8];
    const float* w1    = (const float*)d_in[9];
    const float* b1    = (const float*)d_in[10];
    const float* w2    = (const float*)d_in[11];
    const float* b2    = (const float*)d_in[12];
    float* out = (float*)d_out;

    char* w = (char*)d_ws;
    bf16_t* wbqkv = (bf16_t*)(w + 0);          //  6 MB  [3072,1024] bf16
    bf16_t* wbo   = (bf16_t*)(w + 6291456);    //  2 MB  [1024,1024]
    bf16_t* wb1   = (bf16_t*)(w + 8388608);    //  8 MB  [4096,1024]
    bf16_t* wb2   = (bf16_t*)(w + 16777216);   //  8 MB  [1024,4096]
    bf16_t* h     = (bf16_t*)(w + 25165824);   // 16 MB  [8192,1024] (LN1/LN2 out)
    bf16_t* qkv   = (bf16_t*)(w + 41943040);   // 48 MB  [8192,3072] (V region unused)
    bf16_t* ob    = (bf16_t*)(w + 92274688);   // 16 MB  [8192,1024]
    float*  x1    = (float*)(w + 109051904);   // 32 MB  [8192,1024] fp32
    bf16_t* f     = (bf16_t*)(w + 142606336);  // 64 MB  [8192,4096] (FFN1 out)
    bf16_t* vtb   = (bf16_t*)(w + 142606336);  // 16 MB  [128][64][1024] (aliases f; dead before FFN1)

    // weight converts + LN1 in one dispatch
    prep<<<20480, 256, 0, stream>>>(w_qkv, w_o, w1, w2, wbqkv, wbo, wb1, wb2,
                                    x, ln1g, ln1b, h);
    gemm_bt<3><<<64 * 24, 256, 0, stream>>>(h, wbqkv, b_qkv, nullptr, qkv, nullptr, vtb, 3072, 1024);
    attn_mfma<<<dim3(8, 128), 512, 0, stream>>>(qkv, vtb, ob);
    gemm_bt<2><<<64 * 8, 256, 0, stream>>>(ob, wbo, b_o, x, nullptr, x1, nullptr, 1024, 1024);
    ln_bf16<<<8192, 256, 0, stream>>>(x1, ln2g, ln2b, h);
    gemm_bt<1><<<64 * 32, 256, 0, stream>>>(h, wb1, b1, nullptr, f, nullptr, nullptr, 4096, 1024);
    gemm_bt<2><<<64 * 8, 256, 0, stream>>>(f, wb2, b2, x1, nullptr, out, nullptr, 1024, 4096);
}

// Round 7
// 437.951 us; speedup vs baseline: 1.1558x; 1.0763x over previous
//
#include <hip/hip_runtime.h>
#include <math.h>

// CLIP transformer layer: B=8 S=1024 D=1024 H=16 DH=64 FF=4096, fp32 I/O,
// bf16 MFMA internals. Round 7: attention 256q/block (32q/wave, 45% fewer
// barriers); bf16 residual stream x1 (-48MB traffic).

typedef __bf16 bf16_t;
typedef __bf16 bf16x4 __attribute__((ext_vector_type(4)));
typedef __bf16 bf16x8 __attribute__((ext_vector_type(8)));
typedef float f32x4 __attribute__((ext_vector_type(4)));

// ---------------------------------------------------------------- helpers
__device__ __forceinline__ void async16(const void* g, void* l) {
    // global -> LDS direct DMA, 16B/lane. LDS dest is wave-uniform base + lane*16.
    __builtin_amdgcn_global_load_lds(
        (const __attribute__((address_space(1))) void*)g,
        (__attribute__((address_space(3))) void*)l,
        16, 0, 0);
}

__device__ __forceinline__ void ln_row(const float* __restrict__ x,
                                       const float* __restrict__ g,
                                       const float* __restrict__ bb,
                                       bf16_t* __restrict__ out, int row) {
    const int tid = threadIdx.x;
    const float4 xv = *(const float4*)(x + row * 1024 + tid * 4);
    float s1 = xv.x + xv.y + xv.z + xv.w;
    float s2 = xv.x * xv.x + xv.y * xv.y + xv.z * xv.z + xv.w * xv.w;
#pragma unroll
    for (int m = 32; m >= 1; m >>= 1) {
        s1 += __shfl_xor(s1, m);
        s2 += __shfl_xor(s2, m);
    }
    __shared__ float r1[4], r2[4];
    const int wid = tid >> 6, lane = tid & 63;
    if (lane == 0) { r1[wid] = s1; r2[wid] = s2; }
    __syncthreads();
    s1 = r1[0] + r1[1] + r1[2] + r1[3];
    s2 = r2[0] + r2[1] + r2[2] + r2[3];
    const float mu = s1 * (1.0f / 1024.0f);
    const float var = s2 * (1.0f / 1024.0f) - mu * mu;
    const float rs = rsqrtf(var + 1e-5f);
    const float4 gv = *(const float4*)(g + tid * 4);
    const float4 bv = *(const float4*)(bb + tid * 4);
    bf16x4 o;
    o[0] = (bf16_t)((xv.x - mu) * rs * gv.x + bv.x);
    o[1] = (bf16_t)((xv.y - mu) * rs * gv.y + bv.y);
    o[2] = (bf16_t)((xv.z - mu) * rs * gv.z + bv.z);
    o[3] = (bf16_t)((xv.w - mu) * rs * gv.w + bv.w);
    *(bf16x4*)(out + row * 1024 + tid * 4) = o;
}

// ---------------------------------------------------------------- prep: weight converts (blocks 0..12287) + LN1 (blocks 12288..20479)
__global__ __launch_bounds__(256) void prep(
    const float* __restrict__ s0, const float* __restrict__ s1,
    const float* __restrict__ s2, const float* __restrict__ s3,
    bf16_t* __restrict__ d0, bf16_t* __restrict__ d1,
    bf16_t* __restrict__ d2, bf16_t* __restrict__ d3,
    const float* __restrict__ x, const float* __restrict__ ln1g,
    const float* __restrict__ ln1b, bf16_t* __restrict__ h) {
    if (blockIdx.x >= 12288) {
        ln_row(x, ln1g, ln1b, h, blockIdx.x - 12288);
        return;
    }
    const int g = blockIdx.x * 256 + threadIdx.x;  // float4-group index
    const float* s;
    bf16_t* d;
    int off;
    if (g < 786432)       { s = s0; d = d0; off = g; }            // w_qkv 3M elem
    else if (g < 1048576) { s = s1; d = d1; off = g - 786432; }   // w_o 1M
    else if (g < 2097152) { s = s2; d = d2; off = g - 1048576; }  // w1 4M
    else                  { s = s3; d = d3; off = g - 2097152; }  // w2 4M
    const int i = off * 4;
    const float4 v = *(const float4*)(s + i);
    bf16x4 o;
    o[0] = (bf16_t)v.x; o[1] = (bf16_t)v.y; o[2] = (bf16_t)v.z; o[3] = (bf16_t)v.w;
    *(bf16x4*)(d + i) = o;
}

// ---------------------------------------------------------------- LayerNorm over bf16 input (x1 row of 1024) -> bf16
__global__ __launch_bounds__(256) void ln_b(const bf16_t* __restrict__ x,
                                            const float* __restrict__ g,
                                            const float* __restrict__ bb,
                                            bf16_t* __restrict__ out) {
    const int tid = threadIdx.x;
    const int row = blockIdx.x;
    const bf16x4 xb = *(const bf16x4*)(x + row * 1024 + tid * 4);
    const float x0 = (float)xb[0], x1 = (float)xb[1], x2 = (float)xb[2], x3 = (float)xb[3];
    float s1 = x0 + x1 + x2 + x3;
    float s2 = x0 * x0 + x1 * x1 + x2 * x2 + x3 * x3;
#pragma unroll
    for (int m = 32; m >= 1; m >>= 1) {
        s1 += __shfl_xor(s1, m);
        s2 += __shfl_xor(s2, m);
    }
    __shared__ float r1[4], r2[4];
    const int wid = tid >> 6, lane = tid & 63;
    if (lane == 0) { r1[wid] = s1; r2[wid] = s2; }
    __syncthreads();
    s1 = r1[0] + r1[1] + r1[2] + r1[3];
    s2 = r2[0] + r2[1] + r2[2] + r2[3];
    const float mu = s1 * (1.0f / 1024.0f);
    const float var = s2 * (1.0f / 1024.0f) - mu * mu;
    const float rs = rsqrtf(var + 1e-5f);
    const float4 gv = *(const float4*)(g + tid * 4);
    const float4 bv = *(const float4*)(bb + tid * 4);
    bf16x4 o;
    o[0] = (bf16_t)((x0 - mu) * rs * gv.x + bv.x);
    o[1] = (bf16_t)((x1 - mu) * rs * gv.y + bv.y);
    o[2] = (bf16_t)((x2 - mu) * rs * gv.z + bv.z);
    o[3] = (bf16_t)((x3 - mu) * rs * gv.w + bv.w);
    *(bf16x4*)(out + row * 1024 + tid * 4) = o;
}

// ---------------------------------------------------------------- GEMM: C[M,N] = A[M,K] @ W[N,K]^T + bias
// 128x128 tile, BK=64, XOR-swizzled LDS (conflict-free b128 frag reads),
// 4x4 of 16x16x32 MFMA per wave (measured 0 bank conflicts).
// MODE 1: bias+gelu -> bf16 (FFN1); MODE 3: QKV (Q/K -> bf16, V -> vt);
// MODE 4: bias + fp32 resid -> bf16 (proj); MODE 5: bias + bf16 resid -> fp32 (FFN2).
template <int MODE>
__global__ __launch_bounds__(256, 2) void gemm_bt(
    const bf16_t* __restrict__ A, const bf16_t* __restrict__ W,
    const float* __restrict__ bias, const float* __restrict__ residf,
    const bf16_t* __restrict__ residb,
    bf16_t* __restrict__ outb, float* __restrict__ outf,
    bf16_t* __restrict__ vt, int N, int K) {
    __shared__ bf16_t As[128 * 64];
    __shared__ bf16_t Bs[128 * 64];
    const int tid = threadIdx.x;
    const int w = tid >> 6;
    const int lane = tid & 63;
    const int l15 = lane & 15;
    const int quad = lane >> 4;

    // block swizzle: groups of 8 m-blocks share the n-column (W-tile reuse)
    const int nbn = N >> 7;
    const int per = 8 * nbn;
    const int lid = blockIdx.x;
    const int bm = (lid / per) * 8 + (lid % per) % 8;
    const int bn = (lid % per) / 8;
    const int m0 = bm * 128;
    const int n0 = bn * 128;
    const int wm = (w & 1) * 64;
    const int wn = (w >> 1) * 64;

    // staging: 4 calls/wave per operand; chunk c = q*256 + w*64 + lane (16B each).
    // LDS slot (row r, seg s) holds global k-seg (s ^ (r&7)).
    int rr[4], so[4];
#pragma unroll
    for (int q = 0; q < 4; q++) {
        const int c = q * 256 + w * 64 + lane;
        rr[q] = c >> 3;
        so[q] = ((c & 7) ^ (rr[q] & 7)) * 8;
    }
    const bf16_t* pA[4];
    const bf16_t* pB[4];
#pragma unroll
    for (int q = 0; q < 4; q++) {
        pA[q] = A + (size_t)(m0 + rr[q]) * K + so[q];
        pB[q] = W + (size_t)(n0 + rr[q]) * K + so[q];
    }

    f32x4 acc[4][4] = {};

    for (int k0 = 0; k0 < K; k0 += 64) {
#pragma unroll
        for (int q = 0; q < 4; q++) {
            async16(pA[q], As + q * 2048 + w * 512);
            async16(pB[q], Bs + q * 2048 + w * 512);
            pA[q] += 64; pB[q] += 64;
        }
        __syncthreads();  // drains vmcnt -> LDS tiles visible

        bf16x8 af[4][2], bfr[4][2];
#pragma unroll
        for (int i = 0; i < 4; i++) {
            const int r = wm + i * 16 + l15;
#pragma unroll
            for (int f = 0; f < 2; f++) {
                const int slot = (f * 4 + quad) ^ (r & 7);
                af[i][f] = *(const bf16x8*)(As + r * 64 + slot * 8);
            }
        }
#pragma unroll
        for (int j = 0; j < 4; j++) {
            const int r = wn + j * 16 + l15;
#pragma unroll
            for (int f = 0; f < 2; f++) {
                const int slot = (f * 4 + quad) ^ (r & 7);
                bfr[j][f] = *(const bf16x8*)(Bs + r * 64 + slot * 8);
            }
        }
#pragma unroll
        for (int i = 0; i < 4; i++)
#pragma unroll
            for (int j = 0; j < 4; j++)
#pragma unroll
                for (int f = 0; f < 2; f++)
                    acc[i][j] = __builtin_amdgcn_mfma_f32_16x16x32_bf16(
                        af[i][f], bfr[j][f], acc[i][j], 0, 0, 0);
        __syncthreads();  // protect LDS from next iteration's staging
    }

    // epilogue: C/D layout col=lane&15 (n), row=(lane>>4)*4+reg (m)
#pragma unroll
    for (int i = 0; i < 4; i++) {
#pragma unroll
        for (int j = 0; j < 4; j++) {
            const int col = n0 + wn + j * 16 + l15;
            const float bcol = bias[col];
            const int row0 = m0 + wm + i * 16 + quad * 4;
            float v4[4];
#pragma unroll
            for (int q = 0; q < 4; q++) {
                float v = acc[i][j][q] + bcol;
                if (MODE == 1) {  // tanh-GELU == x * sigmoid(2u)
                    const float u2 = -1.5957691216057308f * (v + 0.044715f * v * v * v);
                    v = v * __builtin_amdgcn_rcpf(1.0f + __expf(u2));
                }
                v4[q] = v;
            }
            if (MODE == 4) {        // + fp32 resid -> bf16 out
#pragma unroll
                for (int q = 0; q < 4; q++) {
                    const size_t idx = (size_t)(row0 + q) * N + col;
                    outb[idx] = (bf16_t)(v4[q] + residf[idx]);
                }
            } else if (MODE == 5) { // + bf16 resid -> fp32 out
#pragma unroll
                for (int q = 0; q < 4; q++) {
                    const size_t idx = (size_t)(row0 + q) * N + col;
                    outf[idx] = v4[q] + (float)residb[idx];
                }
            } else if (MODE == 3 && col >= 2048) {
                // V column -> vt[bh][d][s]; regs q = 4 consecutive s
                const int bh = (row0 >> 10) * 16 + ((col - 2048) >> 6);
                const int d = (col - 2048) & 63;
                bf16x4 pk;
#pragma unroll
                for (int q = 0; q < 4; q++) pk[q] = (bf16_t)v4[q];
                *(bf16x4*)(vt + (size_t)bh * 65536 + d * 1024 + (row0 & 1023)) = pk;
            } else {
#pragma unroll
                for (int q = 0; q < 4; q++)
                    outb[(size_t)(row0 + q) * N + col] = (bf16_t)v4[q];
            }
        }
    }
}

// ---------------------------------------------------------------- MFMA causal flash attention
// Grid (4 q-blocks of 256, 128 bh), 512 thr = 8 waves; wave owns 32 queries
// (two 16-query groups g=0,1). One 64-key tile staged per iteration serves
// all 256 queries: barrier-events per bh drop 72 -> 40 vs round 6.
// S^T = K @ Q^T (C: row=key, col=q=lane&15); O^T = V^T @ P^T (C: row=d, col=q).
__global__ __launch_bounds__(512) void attn_mfma(const bf16_t* __restrict__ qkv,
                                                 const bf16_t* __restrict__ vt,
                                                 bf16_t* __restrict__ o) {
    __shared__ bf16_t Ks[4096];       // [key=64][dseg swizzled]  8KB
    __shared__ bf16_t Vs[4096];       // [d=64][kseg swizzled]    8KB
    __shared__ bf16_t Ps[8][32][72];  // per-wave P[q(32)][key], padded stride 72 (36KB)
    const int tid = threadIdx.x;
    const int w = tid >> 6;           // 0..7
    const int lane = tid & 63;
    const int l15 = lane & 15;
    const int quad = lane >> 4;
    const int qb = blockIdx.x;        // q-block of 256
    const int bh = blockIdx.y;
    const int b = bh >> 4, h = bh & 15;

    const int qrow = b * 1024 + qb * 256 + w * 32;  // wave's first query row (global)

    // Q^T B-frags for both 16-q groups, scaled by 1/8 (exact pow2)
    bf16x8 qf[2][2];
#pragma unroll
    for (int g = 0; g < 2; g++)
#pragma unroll
        for (int f = 0; f < 2; f++) {
            bf16x8 t = *(const bf16x8*)(qkv + (size_t)(qrow + g * 16 + l15) * 3072 + h * 64 + f * 32 + quad * 8);
#pragma unroll
            for (int e = 0; e < 8; e++) t[e] = (bf16_t)((float)t[e] * 0.125f);
            qf[g][f] = t;
        }

    f32x4 Ot[2][4] = {};
    float mrow[2] = {-3.0e38f, -3.0e38f};
    float lrow[2] = {0.0f, 0.0f};

    // staging: 1 call/wave per operand; chunk c = w*64 + lane (16B each)
    const int c0 = w * 64 + lane;
    const int r0 = c0 >> 3, g0 = (((c0 & 7) ^ (r0 & 7))) * 8;

    const bf16_t* kbase = qkv + (size_t)(b * 1024) * 3072 + 1024 + h * 64;
    const bf16_t* vbase = vt + (size_t)bh * 64 * 1024;

    const int ktmax = 4 * qb + 3;  // keys up to qb*256+255
    for (int kt = 0; kt <= ktmax; kt++) {
        async16(kbase + (size_t)(kt * 64 + r0) * 3072 + g0, Ks + w * 512);
        async16(vbase + (size_t)r0 * 1024 + kt * 64 + g0, Vs + w * 512);
        __syncthreads();

#pragma unroll
        for (int g = 0; g < 2; g++) {
            const int qmaxw = qb * 256 + w * 32 + g * 16 + 15;  // group's max query
            if (kt * 64 > qmaxw) continue;  // whole tile masked for this group
            const int ktd = qmaxw >> 6;     // diagonal tile
            const int kbd = (2 * w + g) & 3;

            f32x4 sf[4];
#pragma unroll
            for (int kb = 0; kb < 4; kb++) {
                if (kt * 64 + kb * 16 > qmaxw) {  // fully masked key-block
                    sf[kb] = (f32x4){-3.0e38f, -3.0e38f, -3.0e38f, -3.0e38f};
                    continue;
                }
                const int r = kb * 16 + l15;
                f32x4 acc = {};
#pragma unroll
                for (int f = 0; f < 2; f++) {
                    const int seg = (f * 4 + quad) ^ (r & 7);
                    const bf16x8 kf = *(const bf16x8*)(Ks + r * 64 + seg * 8);
                    acc = __builtin_amdgcn_mfma_f32_16x16x32_bf16(kf, qf[g][f], acc, 0, 0, 0);
                }
                if (kt == ktd && kb == kbd) {  // diagonal 16-block: per-element mask
#pragma unroll
                    for (int rr2 = 0; rr2 < 4; rr2++)
                        if (quad * 4 + rr2 > l15) acc[rr2] = -3.0e38f;
                }
                sf[kb] = acc;
            }

            // online softmax over columns (q = l15)
            float tmax = -3.0e38f;
#pragma unroll
            for (int kb = 0; kb < 4; kb++)
#pragma unroll
                for (int rr2 = 0; rr2 < 4; rr2++) tmax = fmaxf(tmax, sf[kb][rr2]);
            tmax = fmaxf(tmax, __shfl_xor(tmax, 16));
            tmax = fmaxf(tmax, __shfl_xor(tmax, 32));
            const float mnew = fmaxf(mrow[g], tmax);
            const float alpha = __expf(mrow[g] - mnew);
            float psum = 0.0f;
#pragma unroll
            for (int kb = 0; kb < 4; kb++) {
                bf16x4 pk;
#pragma unroll
                for (int rr2 = 0; rr2 < 4; rr2++) {
                    const float p = __expf(sf[kb][rr2] - mnew);
                    psum += p;
                    pk[rr2] = (bf16_t)p;
                }
                *(bf16x4*)(&Ps[w][g * 16 + l15][kb * 16 + quad * 4]) = pk;
            }
            psum += __shfl_xor(psum, 16);
            psum += __shfl_xor(psum, 32);
            lrow[g] = lrow[g] * alpha + psum;
            mrow[g] = mnew;
#pragma unroll
            for (int db = 0; db < 4; db++)
#pragma unroll
                for (int rr2 = 0; rr2 < 4; rr2++) Ot[g][db][rr2] *= alpha;

#pragma unroll
            for (int ks = 0; ks < 2; ks++) {
                if (kt * 64 + ks * 32 > qmaxw) break;  // all-zero P (wave-uniform)
                const bf16x8 pf = *(const bf16x8*)(&Ps[w][g * 16 + l15][ks * 32 + quad * 8]);
#pragma unroll
                for (int db = 0; db < 4; db++) {
                    const int d = db * 16 + l15;
                    const int seg = (ks * 4 + quad) ^ (d & 7);
                    const bf16x8 vf = *(const bf16x8*)(Vs + d * 64 + seg * 8);
                    Ot[g][db] = __builtin_amdgcn_mfma_f32_16x16x32_bf16(vf, pf, Ot[g][db], 0, 0, 0);
                }
            }
        }
        __syncthreads();  // protect Ks/Vs before next staging
    }

#pragma unroll
    for (int g = 0; g < 2; g++) {
        const float rl = 1.0f / lrow[g];
#pragma unroll
        for (int db = 0; db < 4; db++) {
            bf16x4 ov;
#pragma unroll
            for (int rr2 = 0; rr2 < 4; rr2++) ov[rr2] = (bf16_t)(Ot[g][db][rr2] * rl);
            *(bf16x4*)(o + (size_t)(qrow + g * 16 + l15) * 1024 + h * 64 + db * 16 + quad * 4) = ov;
        }
    }
}

// ---------------------------------------------------------------- launch
extern "C" void kernel_launch(void* const* d_in, const int* in_sizes, int n_in,
                              void* d_out, int out_size, void* d_ws, size_t ws_size,
                              hipStream_t stream) {
    const float* x     = (const float*)d_in[0];
    const float* ln1g  = (const float*)d_in[1];
    const float* ln1b  = (const float*)d_in[2];
    const float* w_qkv = (const float*)d_in[3];
    const float* b_qkv = (const float*)d_in[4];
    const float* w_o   = (const float*)d_in[5];
    const float* b_o   = (const float*)d_in[6];
    const float* ln2g  = (const float*)d_in[7];
    const float* ln2b  = (const float*)d_in[8];
    const float* w1    = (const float*)d_in[9];
    const float* b1    = (const float*)d_in[10];
    const float* w2    = (const float*)d_in[11];
    const float* b2    = (const float*)d_in[12];
    float* out = (float*)d_out;

    char* w = (char*)d_ws;
    bf16_t* wbqkv = (bf16_t*)(w + 0);          //  6 MB  [3072,1024] bf16
    bf16_t* wbo   = (bf16_t*)(w + 6291456);    //  2 MB  [1024,1024]
    bf16_t* wb1   = (bf16_t*)(w + 8388608);    //  8 MB  [4096,1024]
    bf16_t* wb2   = (bf16_t*)(w + 16777216);   //  8 MB  [1024,4096]
    bf16_t* h     = (bf16_t*)(w + 25165824);   // 16 MB  [8192,1024] (LN1/LN2 out)
    bf16_t* qkv   = (bf16_t*)(w + 41943040);   // 48 MB  [8192,3072] (V region unused)
    bf16_t* ob    = (bf16_t*)(w + 92274688);   // 16 MB  [8192,1024]
    bf16_t* x1b   = (bf16_t*)(w + 109051904);  // 16 MB  [8192,1024] bf16 residual stream
    bf16_t* f     = (bf16_t*)(w + 142606336);  // 64 MB  [8192,4096] (FFN1 out)
    bf16_t* vtb   = (bf16_t*)(w + 142606336);  // 16 MB  [128][64][1024] (aliases f; dead before FFN1)

    // weight converts + LN1 in one dispatch
    prep<<<20480, 256, 0, stream>>>(w_qkv, w_o, w1, w2, wbqkv, wbo, wb1, wb2,
                                    x, ln1g, ln1b, h);
    gemm_bt<3><<<64 * 24, 256, 0, stream>>>(h, wbqkv, b_qkv, nullptr, nullptr, qkv, nullptr, vtb, 3072, 1024);
    attn_mfma<<<dim3(4, 128), 512, 0, stream>>>(qkv, vtb, ob);
    // x1b = bf16(x + ob @ w_o^T + b_o)
    gemm_bt<4><<<64 * 8, 256, 0, stream>>>(ob, wbo, b_o, x, nullptr, x1b, nullptr, nullptr, 1024, 1024);
    ln_b<<<8192, 256, 0, stream>>>(x1b, ln2g, ln2b, h);
    gemm_bt<1><<<64 * 32, 256, 0, stream>>>(h, wb1, b1, nullptr, nullptr, f, nullptr, nullptr, 4096, 1024);
    // out = x1b + f @ w2^T + b2  (fp32 out)
    gemm_bt<5><<<64 * 8, 256, 0, stream>>>(f, wb2, b2, nullptr, x1b, nullptr, out, nullptr, 1024, 4096);
}